// Round 5
// baseline (52.819 us; speedup 1.0000x reference)
//
#include <hip/hip_runtime.h>

#define BB 8
#define HH 256
#define WW 256
#define BHW (BB*HH*WW)
#define BIGV 512.0f

// ws layout:
//   [0, 2*BHW) u32   : packed g (lo16 = fg dist, hi16 = bg dist), [ip][b][h][w]
//   then 256 ints    : per-edt-block any-fg flags (slot = blockIdx)
//   then BB*HH floats: per-row partial sums
//   then 1 u32       : done-counter for last-block-done reduction

// Vertical EDT via min-plus segmented scan, both channels in one pass.
// grid = 2(input)*8(batch)*16(col tile) = 256 blocks, 256 threads.
// thread: c = t&15 (column in tile), s = t>>4 (16-row segment).
__global__ __launch_bounds__(256) void edt_vert(const float* __restrict__ x,
                                                const float* __restrict__ y,
                                                unsigned int* __restrict__ gpack,
                                                int* __restrict__ blkflag,
                                                unsigned int* __restrict__ done) {
    __shared__ float Cf[2][16][16];   // [ch][seg][col]: dist from seg END to last zero (1e9 if none)
    __shared__ float Cb[2][16][16];   // [ch][seg][col]: dist from seg START to first zero
    __shared__ int sAny;

    int blk = blockIdx.x;
    int tileIdx = blk & 15;
    int b  = (blk >> 4) & 7;
    int ip = blk >> 7;
    int t = threadIdx.x;
    int c = t & 15, s = t >> 4;

    if (t == 0) sAny = 0;
    if (blk == 0 && t == 0) *done = 0u;   // reset counter (ordered before row_pass)

    const float* src = (ip ? y : x) + (size_t)b*HH*WW + tileIdx*16 + c;

    // Load 16 rows once; keep mask bits.
    unsigned m = 0;
    const float* p = src + (size_t)(s*16)*WW;
    #pragma unroll
    for (int i = 0; i < 16; ++i) {
        if (p[(size_t)i*WW] > 0.5f) m |= (1u << i);
    }

    // Segment summaries. ch0 (fg EDT): zeros where bit CLEAR; ch1 (bg EDT): zeros where bit SET.
    unsigned invm = (~m) & 0xFFFFu;
    Cf[0][s][c] = invm ? (float)(15 - (31 - __clz((int)invm))) : 1e9f;
    Cb[0][s][c] = invm ? (float)(__ffs((int)invm) - 1)          : 1e9f;
    Cf[1][s][c] = m    ? (float)(15 - (31 - __clz((int)m)))     : 1e9f;
    Cb[1][s][c] = m    ? (float)(__ffs((int)m) - 1)             : 1e9f;
    __syncthreads();
    if (m) sAny = 1;   // benign LDS race, all writers store 1

    // Carries entering this segment — fully unrolled, predicated.
    float e0 = BIGV, e1 = BIGV;
    #pragma unroll
    for (int sp = 0; sp < 15; ++sp) {
        float c0 = Cf[0][sp][c], c1 = Cf[1][sp][c];
        bool act = sp < s;
        e0 = act ? fminf(fminf(e0 + 16.0f, BIGV), c0) : e0;
        e1 = act ? fminf(fminf(e1 + 16.0f, BIGV), c1) : e1;
    }
    float f0 = BIGV, f1 = BIGV;
    #pragma unroll
    for (int sp = 15; sp >= 1; --sp) {
        float c0 = Cb[0][sp][c], c1 = Cb[1][sp][c];
        bool act = sp > s;
        f0 = act ? fminf(fminf(f0 + 16.0f, BIGV), c0) : f0;
        f1 = act ? fminf(fminf(f1 + 16.0f, BIGV), c1) : f1;
    }

    // Exact detail pass, both channels, pack u16 pair per pixel.
    float b0v[16], b1v[16];
    float d0 = f0, d1 = f1;
    #pragma unroll
    for (int i = 15; i >= 0; --i) {
        bool bit = (m >> i) & 1u;
        d0 = !bit ? 0.0f : fminf(d0 + 1.0f, BIGV);
        d1 =  bit ? 0.0f : fminf(d1 + 1.0f, BIGV);
        b0v[i] = d0; b1v[i] = d1;
    }
    size_t base = (size_t)(ip*BB + b)*HH*WW + tileIdx*16 + c;
    d0 = e0; d1 = e1;
    #pragma unroll
    for (int i = 0; i < 16; ++i) {
        bool bit = (m >> i) & 1u;
        d0 = !bit ? 0.0f : fminf(d0 + 1.0f, BIGV);
        d1 =  bit ? 0.0f : fminf(d1 + 1.0f, BIGV);
        float g0 = fminf(d0, b0v[i]);
        float g1 = fminf(d1, b1v[i]);
        unsigned int pk = (unsigned int)(int)g0 | ((unsigned int)(int)g1 << 16);
        gpack[base + (size_t)(s*16 + i)*WW] = pk;
    }

    __syncthreads();
    if (t == 0) blkflag[blk] = sAny;   // every block writes its own slot: no init needed
}

// Horizontal pass: outward early-exit min search + fused loss + per-row partial
// + last-block-done final reduction (fixed-order, deterministic).
__global__ __launch_bounds__(256) void row_pass(const float* __restrict__ x,
                                                const float* __restrict__ y,
                                                const unsigned int* __restrict__ gpack,
                                                const int* __restrict__ blkflag,
                                                float* __restrict__ partials,
                                                unsigned int* __restrict__ done,
                                                float* __restrict__ out) {
    __shared__ float4 sp[768];
    __shared__ float wsum[4];
    __shared__ float sF[2];
    __shared__ int sLast;
    int bh = blockIdx.x;          // b*HH + h
    int b  = bh >> 8;
    int j  = threadIdx.x;
    size_t rowoff = (size_t)bh * WW;

    float xv = x[rowoff + j];
    float yv = y[rowoff + j];
    unsigned int px = gpack[rowoff + j];                        // x channels
    unsigned int py = gpack[(size_t)BHW + rowoff + j];          // y channels
    int g0 = px & 0xFFFFu, g1 = px >> 16;
    int g2v = py & 0xFFFFu, g3 = py >> 16;
    float v0 = (float)(g0*g0), v1 = (float)(g1*g1);
    float v2 = (float)(g2v*g2v), v3 = (float)(g3*g3);

    float4 big = make_float4(1e9f, 1e9f, 1e9f, 1e9f);
    sp[j] = big;
    sp[j+512] = big;
    sp[j+256] = make_float4(v0, v1, v2, v3);

    if (j < 64) {   // wave 0: gather has_fg flags (OR over 16 tile slots per input)
        int v = 0;
        if (j < 32) v = blkflag[((j < 16) ? 0 : 128) + b * 16 + (j & 15)];
        unsigned long long ball = __ballot(v != 0);
        if (j == 0) {
            sF[0] = (ball & 0xFFFFull) ? 1.0f : 0.0f;
            sF[1] = ((ball >> 16) & 0xFFFFull) ? 1.0f : 0.0f;
        }
    }
    __syncthreads();

    float b0 = v0, b1 = v1, b2 = v2, b3 = v3;
    for (int dl = 1; dl < 256; ++dl) {
        float d2 = (float)(dl * dl);
        float bmax = fmaxf(fmaxf(b0, b1), fmaxf(b2, b3));
        if (!__any(d2 < bmax)) break;     // no candidate can improve any lane in wave
        float4 L = sp[j + 256 - dl];
        float4 R = sp[j + 256 + dl];
        b0 = fminf(b0, d2 + fminf(L.x, R.x));
        b1 = fminf(b1, d2 + fminf(L.y, R.y));
        b2 = fminf(b2, d2 + fminf(L.z, R.z));
        b3 = fminf(b3, d2 + fminf(L.w, R.w));
    }

    float dtx = sF[0] != 0.0f ? (sqrtf(b0) + sqrtf(b1)) : 0.0f;
    float dty = sF[1] != 0.0f ? (sqrtf(b2) + sqrtf(b3)) : 0.0f;
    float e = xv - yv;
    float val = e * e * (dtx * dtx + dty * dty);

    for (int off = 32; off; off >>= 1) val += __shfl_down(val, off, 64);
    if ((j & 63) == 0) wsum[j >> 6] = val;
    __syncthreads();
    if (j == 0) {
        partials[bh] = wsum[0] + wsum[1] + wsum[2] + wsum[3];
        __threadfence();                          // release partials (agent scope)
        unsigned int old = atomicAdd(done, 1u);   // device-scope RMW
        sLast = (old == (unsigned int)(gridDim.x - 1)) ? 1 : 0;
    }
    __syncthreads();
    if (sLast) {                                  // uniform branch: whole block
        __threadfence();                          // acquire side
        float s = 0.0f;
        #pragma unroll
        for (int i = 0; i < 8; ++i)
            s += __hip_atomic_load(&partials[i * 256 + j],
                                   __ATOMIC_RELAXED, __HIP_MEMORY_SCOPE_AGENT);
        for (int off = 32; off; off >>= 1) s += __shfl_down(s, off, 64);
        if ((j & 63) == 0) wsum[j >> 6] = s;
        __syncthreads();
        if (j == 0) out[0] = (wsum[0] + wsum[1] + wsum[2] + wsum[3]) * (1.0f / (float)BHW);
    }
}

extern "C" void kernel_launch(void* const* d_in, const int* in_sizes, int n_in,
                              void* d_out, int out_size, void* d_ws, size_t ws_size,
                              hipStream_t stream) {
    const float* x = (const float*)d_in[0];
    const float* y = (const float*)d_in[1];
    float* out = (float*)d_out;

    char* ws = (char*)d_ws;
    unsigned int* gpack = (unsigned int*)ws;                            // 2*BHW u32
    int* blkflag = (int*)(ws + (size_t)2 * BHW * sizeof(unsigned int)); // 256 ints
    float* partials = (float*)(ws + (size_t)2 * BHW * sizeof(unsigned int) + 256 * sizeof(int));
    unsigned int* done = (unsigned int*)(ws + (size_t)2 * BHW * sizeof(unsigned int)
                                            + 256 * sizeof(int) + (size_t)BB * HH * sizeof(float));

    edt_vert<<<256, 256, 0, stream>>>(x, y, gpack, blkflag, done);
    row_pass<<<BB * HH, 256, 0, stream>>>(x, y, gpack, blkflag, partials, done, out);
}

// Round 6
// 15.298 us; speedup vs baseline: 3.4528x; 3.4528x over previous
//
#include <hip/hip_runtime.h>

#define BB 8
#define HH 256
#define WW 256
#define BHW (BB*HH*WW)
#define BIGV 512.0f

// ws layout:
//   [0, 2*BHW) u16   : g distance per pixel, [ip][b][h][w].  Exactly one of
//                      (fg-dist, bg-dist) is nonzero per pixel; the mask bit
//                      (recomputed from the input in row_pass) selects which.
//   then 256 ints    : per-edt-block any-fg flags (slot = blockIdx)
//   then BB*HH floats: per-row partial sums

// Vertical EDT via min-plus segmented scan, both channels in one pass.
// grid = 2(input)*8(batch)*16(col tile) = 256 blocks, 256 threads.
// thread: c = t&15 (column in tile), s = t>>4 (16-row segment).
__global__ __launch_bounds__(256) void edt_vert(const float* __restrict__ x,
                                                const float* __restrict__ y,
                                                unsigned short* __restrict__ gdist,
                                                int* __restrict__ blkflag) {
    __shared__ float Cf[2][16][16];   // [ch][seg][col]: dist from seg END to last zero (1e9 if none)
    __shared__ float Cb[2][16][16];   // [ch][seg][col]: dist from seg START to first zero
    __shared__ int sAny;

    int blk = blockIdx.x;
    int tileIdx = blk & 15;
    int b  = (blk >> 4) & 7;
    int ip = blk >> 7;
    int t = threadIdx.x;
    int c = t & 15, s = t >> 4;

    if (t == 0) sAny = 0;

    const float* src = (ip ? y : x) + (size_t)b*HH*WW + tileIdx*16 + c;

    // Load 16 rows once; keep mask bits.
    unsigned m = 0;
    const float* p = src + (size_t)(s*16)*WW;
    #pragma unroll
    for (int i = 0; i < 16; ++i) {
        if (p[(size_t)i*WW] > 0.5f) m |= (1u << i);
    }

    // Segment summaries. ch0 (fg EDT): zeros where bit CLEAR; ch1 (bg EDT): zeros where bit SET.
    unsigned invm = (~m) & 0xFFFFu;
    Cf[0][s][c] = invm ? (float)(15 - (31 - __clz((int)invm))) : 1e9f;
    Cb[0][s][c] = invm ? (float)(__ffs((int)invm) - 1)          : 1e9f;
    Cf[1][s][c] = m    ? (float)(15 - (31 - __clz((int)m)))     : 1e9f;
    Cb[1][s][c] = m    ? (float)(__ffs((int)m) - 1)             : 1e9f;
    __syncthreads();
    if (m) sAny = 1;   // benign LDS race, all writers store 1

    // Carries entering this segment — fully unrolled, predicated:
    // all ds_read addresses static -> issue together, single lgkmcnt wait.
    float e0 = BIGV, e1 = BIGV;
    #pragma unroll
    for (int sp = 0; sp < 15; ++sp) {
        float c0 = Cf[0][sp][c], c1 = Cf[1][sp][c];
        bool act = sp < s;
        e0 = act ? fminf(fminf(e0 + 16.0f, BIGV), c0) : e0;
        e1 = act ? fminf(fminf(e1 + 16.0f, BIGV), c1) : e1;
    }
    float f0 = BIGV, f1 = BIGV;
    #pragma unroll
    for (int sp = 15; sp >= 1; --sp) {
        float c0 = Cb[0][sp][c], c1 = Cb[1][sp][c];
        bool act = sp > s;
        f0 = act ? fminf(fminf(f0 + 16.0f, BIGV), c0) : f0;
        f1 = act ? fminf(fminf(f1 + 16.0f, BIGV), c1) : f1;
    }

    // Exact detail pass, both channels; store the single nonzero distance as u16.
    float b0v[16], b1v[16];
    float d0 = f0, d1 = f1;
    #pragma unroll
    for (int i = 15; i >= 0; --i) {
        bool bit = (m >> i) & 1u;
        d0 = !bit ? 0.0f : fminf(d0 + 1.0f, BIGV);
        d1 =  bit ? 0.0f : fminf(d1 + 1.0f, BIGV);
        b0v[i] = d0; b1v[i] = d1;
    }
    size_t base = (size_t)(ip*BB + b)*HH*WW + tileIdx*16 + c;
    d0 = e0; d1 = e1;
    #pragma unroll
    for (int i = 0; i < 16; ++i) {
        bool bit = (m >> i) & 1u;
        d0 = !bit ? 0.0f : fminf(d0 + 1.0f, BIGV);
        d1 =  bit ? 0.0f : fminf(d1 + 1.0f, BIGV);
        float g0 = fminf(d0, b0v[i]);   // fg-EDT dist (nonzero only on fg pixels)
        float g1 = fminf(d1, b1v[i]);   // bg-EDT dist (nonzero only on bg pixels)
        float gs = bit ? g0 : g1;       // exactly one is nonzero; mask bit selects
        gdist[base + (size_t)(s*16 + i)*WW] = (unsigned short)(int)gs;
    }

    __syncthreads();
    if (t == 0) blkflag[blk] = sAny;   // every block writes its own slot: no init needed
}

// Horizontal pass: outward early-exit min search + fused loss + per-row partial.
__global__ __launch_bounds__(256) void row_pass(const float* __restrict__ x,
                                                const float* __restrict__ y,
                                                const unsigned short* __restrict__ gdist,
                                                const int* __restrict__ blkflag,
                                                float* __restrict__ partials) {
    __shared__ float sp0[768], sp1[768], sp2[768], sp3[768];
    __shared__ float wsum[4];
    __shared__ float sF[2];
    int bh = blockIdx.x;          // b*HH + h
    int b  = bh >> 8;
    int j  = threadIdx.x;
    size_t rowoff = (size_t)bh * WW;

    float xv = x[rowoff + j];
    float yv = y[rowoff + j];
    int gx = gdist[rowoff + j];                       // x: single nonzero dist
    int gy = gdist[(size_t)BHW + rowoff + j];         // y: single nonzero dist
    bool mx = xv > 0.5f;                              // identical compare to edt_vert
    bool my = yv > 0.5f;
    int gx2 = gx * gx, gy2 = gy * gy;                 // <= 512^2, exact in f32
    float v0 = (float)(mx ? gx2 : 0);                 // x fg-EDT g^2
    float v1 = (float)(mx ? 0 : gx2);                 // x bg-EDT g^2
    float v2 = (float)(my ? gy2 : 0);                 // y fg-EDT g^2
    float v3 = (float)(my ? 0 : gy2);                 // y bg-EDT g^2

    sp0[j] = 1e9f; sp1[j] = 1e9f; sp2[j] = 1e9f; sp3[j] = 1e9f;
    sp0[j+512] = 1e9f; sp1[j+512] = 1e9f; sp2[j+512] = 1e9f; sp3[j+512] = 1e9f;
    sp0[j+256] = v0; sp1[j+256] = v1; sp2[j+256] = v2; sp3[j+256] = v3;

    if (j < 64) {   // wave 0: gather has_fg flags (OR over 16 tile slots per input)
        int v = 0;
        if (j < 32) v = blkflag[((j < 16) ? 0 : 128) + b * 16 + (j & 15)];
        unsigned long long ball = __ballot(v != 0);
        if (j == 0) {
            sF[0] = (ball & 0xFFFFull) ? 1.0f : 0.0f;
            sF[1] = ((ball >> 16) & 0xFFFFull) ? 1.0f : 0.0f;
        }
    }
    __syncthreads();

    float b0 = v0, b1 = v1, b2 = v2, b3 = v3;
    for (int dl = 1; dl < 256; ++dl) {
        float d2 = (float)(dl * dl);
        float bmax = fmaxf(fmaxf(b0, b1), fmaxf(b2, b3));
        if (!__any(d2 < bmax)) break;     // no candidate can improve any lane in wave
        int l = j + 256 - dl, r = j + 256 + dl;
        b0 = fminf(b0, fminf(d2 + sp0[l], d2 + sp0[r]));
        b1 = fminf(b1, fminf(d2 + sp1[l], d2 + sp1[r]));
        b2 = fminf(b2, fminf(d2 + sp2[l], d2 + sp2[r]));
        b3 = fminf(b3, fminf(d2 + sp3[l], d2 + sp3[r]));
    }

    float dtx = sF[0] != 0.0f ? (sqrtf(b0) + sqrtf(b1)) : 0.0f;
    float dty = sF[1] != 0.0f ? (sqrtf(b2) + sqrtf(b3)) : 0.0f;
    float e = xv - yv;
    float val = e * e * (dtx * dtx + dty * dty);

    for (int off = 32; off; off >>= 1) val += __shfl_down(val, off, 64);
    if ((j & 63) == 0) wsum[j >> 6] = val;
    __syncthreads();
    if (j == 0) partials[bh] = wsum[0] + wsum[1] + wsum[2] + wsum[3];
}

__global__ __launch_bounds__(256) void final_reduce(const float* __restrict__ partials,
                                                    float* __restrict__ out) {
    __shared__ float wsum[4];
    int j = threadIdx.x;
    float s = 0.0f;
    #pragma unroll
    for (int i = 0; i < 8; ++i) s += partials[i * 256 + j];
    for (int off = 32; off; off >>= 1) s += __shfl_down(s, off, 64);
    if ((j & 63) == 0) wsum[j >> 6] = s;
    __syncthreads();
    if (j == 0) out[0] = (wsum[0] + wsum[1] + wsum[2] + wsum[3]) * (1.0f / (float)BHW);
}

extern "C" void kernel_launch(void* const* d_in, const int* in_sizes, int n_in,
                              void* d_out, int out_size, void* d_ws, size_t ws_size,
                              hipStream_t stream) {
    const float* x = (const float*)d_in[0];
    const float* y = (const float*)d_in[1];
    float* out = (float*)d_out;

    char* ws = (char*)d_ws;
    unsigned short* gdist = (unsigned short*)ws;                          // 2*BHW u16
    int* blkflag = (int*)(ws + (size_t)2 * BHW * sizeof(unsigned short)); // 256 ints
    float* partials = (float*)(ws + (size_t)2 * BHW * sizeof(unsigned short) + 256 * sizeof(int));

    edt_vert<<<256, 256, 0, stream>>>(x, y, gdist, blkflag);
    row_pass<<<BB * HH, 256, 0, stream>>>(x, y, gdist, blkflag, partials);
    final_reduce<<<1, 256, 0, stream>>>(partials, out);
}